// Round 5
// baseline (372.046 us; speedup 1.0000x reference)
//
#include <hip/hip_runtime.h>
#include <stdint.h>

// Sparse strided conv: scatter (features@W1 -> grid) + gather (grid@W2 -> out).
// R5: latency-bound fix = fewer memory requests + better grid shape:
//   - grid intermediate + staged features in bf16 (half the loads/pair)
//   - packed bf16 atomics (global_atomic_pk_add_bf16): 32 ops/pair, was 64
//   - VPW 256->128: 6345 blocks = 3.1 occupancy rounds (was 1.56 -> 60% occ)

#define N_VOX 120000
#define IC 32
#define OC 64
#define NKV 27
#define DZ 21
#define HY 200
#define WX 176
#define TBL_BITS 20
#define TBL_SIZE (1 << TBL_BITS)
#define TBL_MASK (TBL_SIZE - 1)
#define MAXROWS 480000
#define VPW 128                    // voxels scanned per wave
#define VPBLK (VPW * 4)            // per 4-wave block

// ws layout (bytes)
#define OFF_KEYS 0
#define OFF_VALS 4194304
#define OFF_CNT 8388608
#define OFF_ROWS 8388864           // 27*120000*4 = 12,960,000
#define OFF_FEATB 21348864         // 120000*32*2 = 7,680,000
#define OFF_GRID 29028864          // MAXROWS*64*2 = 61,440,000
#define WS_NEEDED (OFF_GRID + (size_t)MAXROWS * OC * 2)

__device__ __forceinline__ uint32_t hash_lin(int lin) {
    return ((uint32_t)lin * 2654435761u) >> (32 - TBL_BITS);
}

__device__ __forceinline__ void atomAddF32(float* p, float v) {
    unsafeAtomicAdd(p, v);  // global_atomic_add_f32 on gfx950
}

__device__ __forceinline__ void atomPkBf16(uint16_t* p, uint32_t v) {
    asm volatile("global_atomic_pk_add_bf16 %0, %1, off" :: "v"(p), "v"(v) : "memory");
}

// RTNE f32 -> bf16 pair pack
__device__ __forceinline__ uint32_t pk_bf16(float a, float b) {
    uint32_t x = __float_as_uint(a), y = __float_as_uint(b);
    x = (x + 0x7fffu + ((x >> 16) & 1u)) >> 16;
    y = (y + 0x7fffu + ((y >> 16) & 1u)) >> 16;
    return x | (y << 16);
}

__device__ __forceinline__ float bf_lo(uint32_t u) { return __uint_as_float(u << 16); }
__device__ __forceinline__ float bf_hi(uint32_t u) { return __uint_as_float(u & 0xffff0000u); }

__global__ void k_init(int* keys, float* out, int* counter,
                       const float2* __restrict__ feat2, uint32_t* featb) {
    int i = blockIdx.x * blockDim.x + threadIdx.x;
    int stride = gridDim.x * blockDim.x;
    for (int j = i; j < N_VOX * IC; j += stride) out[j] = 0.f;
    for (int j = i; j < TBL_SIZE; j += stride) keys[j] = -1;
    for (int j = i; j < N_VOX * IC / 2; j += stride) {
        float2 f = feat2[j];
        featb[j] = pk_bf16(f.x, f.y);
    }
    if (i == 0) *counter = 0;
}

__global__ void k_build(const int* __restrict__ coors, int* keys, int* rows) {
    int v = blockIdx.x * blockDim.x + threadIdx.x;
    if (v >= N_VOX) return;
    int b = coors[v * 4 + 0];
    int z = coors[v * 4 + 1];
    int y = coors[v * 4 + 2];
    int x = coors[v * 4 + 3];
#pragma unroll
    for (int kv = 0; kv < NKV; ++kv) {
        int oz = kv / 9, oy = (kv / 3) % 3, ox = kv % 3;
        int az = z + 1 - oz, ay = y + 1 - oy, ax = x + 1 - ox;
        int slot = -1;
        bool valid = (az >= 0) && !(az & 1) && ((az >> 1) < DZ) &&
                     (ay >= 0) && !(ay & 1) && ((ay >> 1) < HY) &&
                     (ax >= 0) && !(ax & 1) && ((ax >> 1) < WX);
        if (valid) {
            int lin = ((b * DZ + (az >> 1)) * HY + (ay >> 1)) * WX + (ax >> 1);
            uint32_t h = hash_lin(lin);
            for (;;) {
                int k = atomicCAS(&keys[h], -1, lin);
                if (k == -1 || k == lin) { slot = (int)h; break; }
                h = (h + 1) & TBL_MASK;
            }
        }
        rows[kv * N_VOX + v] = slot;
    }
}

// Block-aggregated compaction (1 atomic/block) + fused zeroing of the block's
// contiguous claimed row range [base, base+total).
__global__ __launch_bounds__(256) void k_assign(const int* __restrict__ keys,
                                                int* __restrict__ vals,
                                                int* counter,
                                                float4* __restrict__ grid4) {
    const int t = threadIdx.x;
    const int s0 = blockIdx.x * 2048 + t * 8;
    const int4 a = ((const int4*)(keys + s0))[0];
    const int4 b = ((const int4*)(keys + s0))[1];
    int k[8] = {a.x, a.y, a.z, a.w, b.x, b.y, b.z, b.w};
    int c = 0;
#pragma unroll
    for (int i = 0; i < 8; ++i) c += (k[i] != -1);

    __shared__ int sc[256];
    __shared__ int base;
    sc[t] = c;
    __syncthreads();
#pragma unroll
    for (int d = 1; d < 256; d <<= 1) {
        int y = (t >= d) ? sc[t - d] : 0;
        __syncthreads();
        sc[t] += y;
        __syncthreads();
    }
    if (t == 255) base = atomicAdd(counter, sc[255]);
    __syncthreads();
    const int total = sc[255];
    int r = base + sc[t] - c;  // exclusive prefix
#pragma unroll
    for (int i = 0; i < 8; ++i) {
        if (k[i] != -1) { vals[s0 + i] = (r < MAXROWS) ? r : -1; ++r; }
    }
    // fused grid zero: rows [base, base+total), 128B (bf16 row) each.
    int zs = min(base, MAXROWS), ze = min(base + total, MAXROWS);
    float4 zz = {0.f, 0.f, 0.f, 0.f};
    for (int i = zs * 8 + t; i < ze * 8; i += 256) grid4[i] = zz;
}

__global__ void k_rows_fix(int* rows, const int* __restrict__ vals) {
    int i = blockIdx.x * blockDim.x + threadIdx.x;
    if (i >= NKV * N_VOX) return;
    int s = rows[i];
    rows[i] = (s >= 0) ? vals[s] : -1;
}

// Ballot-compact valid (v,row) pairs of this wave's VPW voxels into its LDS
// region. One wave only -> no barrier needed.
__device__ __forceinline__ int compact_pairs(const int* __restrict__ rkv,
                                             int v0, int lane, int2* ls) {
    int n = 0;
#pragma unroll
    for (int ch = 0; ch < VPW / 64; ++ch) {
        int v = v0 + ch * 64 + lane;
        int row = (v < N_VOX) ? rkv[v] : -1;
        unsigned long long m = __ballot(row >= 0);
        int pos = n + (int)__popcll(m & ((1ULL << lane) - 1));
        if (row >= 0) ls[pos] = make_int2(v, row);
        n += (int)__popcll(m);
    }
    return n;
}

// 4 independent waves/block; lane = output channel o. W1[kv] column in 32 VGPR.
// Feature row = 32 bf16 = 64B = 4x16B broadcast. Packed bf16 atomics to grid.
__global__ __launch_bounds__(256, 8) void k_scatter(
    const uint4* __restrict__ featb, const float* __restrict__ W1,
    const int* __restrict__ rows, uint16_t* gridb) {
    const int kv = blockIdx.y;
    const int wid = threadIdx.x >> 6;
    const int lane = threadIdx.x & 63;
    __shared__ int2 ls[4][VPW];

    float w[IC];
#pragma unroll
    for (int c = 0; c < IC; ++c) w[c] = W1[(kv * IC + c) * OC + lane];

    const int v0 = (blockIdx.x * 4 + wid) * VPW;
    const int n = (v0 < N_VOX)
                      ? compact_pairs(rows + kv * N_VOX, v0, lane, ls[wid])
                      : 0;

    for (int p = 0; p < n; p += 2) {
        const bool hasB = (p + 1 < n);
        const int2 A = ls[wid][p];
        const int2 B = ls[wid][hasB ? p + 1 : p];
        const uint4* pA = featb + A.x * 4;  // 32 bf16 = 4 x uint4
        const uint4* pB = featb + B.x * 4;
        uint4 fA[4], fB[4];
#pragma unroll
        for (int j = 0; j < 4; ++j) { fA[j] = pA[j]; fB[j] = pB[j]; }
        float accA = 0.f, accB = 0.f;
#pragma unroll
        for (int j = 0; j < 4; ++j) {
            const uint32_t ua[4] = {fA[j].x, fA[j].y, fA[j].z, fA[j].w};
            const uint32_t ub[4] = {fB[j].x, fB[j].y, fB[j].z, fB[j].w};
#pragma unroll
            for (int m = 0; m < 4; ++m) {
                const int cb = j * 8 + m * 2;  // uint4 j = ch [8j,8j+8)
                accA = fmaf(bf_lo(ua[m]), w[cb + 0], accA);
                accA = fmaf(bf_hi(ua[m]), w[cb + 1], accA);
                accB = fmaf(bf_lo(ub[m]), w[cb + 0], accB);
                accB = fmaf(bf_hi(ub[m]), w[cb + 1], accB);
            }
        }
        // packed atomic: even lane adds channels (lane, lane+1)
        float oA = __shfl_xor(accA, 1, 64);
        float oB = __shfl_xor(accB, 1, 64);
        if ((lane & 1) == 0) {
            atomPkBf16(gridb + (size_t)A.y * OC + lane, pk_bf16(accA, oA));
            if (hasB) atomPkBf16(gridb + (size_t)B.y * OC + lane, pk_bf16(accB, oB));
        }
    }
}

// 4 independent waves/block; lane = (h, c). W2[kv] half-column in 32 VGPRs.
// Grid half-row = 32 bf16 = 64B = 4x16B broadcast. shfl_xor(32) combine.
__global__ __launch_bounds__(256, 8) void k_gather(
    const uint16_t* __restrict__ gridb, const float* __restrict__ W2,
    const int* __restrict__ rows, float* out) {
    const int kv = blockIdx.y;
    const int wid = threadIdx.x >> 6;
    const int lane = threadIdx.x & 63;
    const int h = lane >> 5;
    const int c = lane & 31;
    __shared__ int2 ls[4][VPW];

    float w[32];
#pragma unroll
    for (int j = 0; j < 32; ++j) w[j] = W2[(kv * OC + h * 32 + j) * IC + c];

    const int v0 = (blockIdx.x * 4 + wid) * VPW;
    const int n = (v0 < N_VOX)
                      ? compact_pairs(rows + kv * N_VOX, v0, lane, ls[wid])
                      : 0;

    for (int p = 0; p < n; p += 2) {
        const bool hasB = (p + 1 < n);
        const int2 A = ls[wid][p];
        const int2 B = ls[wid][hasB ? p + 1 : p];
        const uint4* pA = (const uint4*)(gridb + (size_t)A.y * OC + h * 32);
        const uint4* pB = (const uint4*)(gridb + (size_t)B.y * OC + h * 32);
        uint4 gA[4], gB[4];
#pragma unroll
        for (int j = 0; j < 4; ++j) { gA[j] = pA[j]; gB[j] = pB[j]; }
        float accA = 0.f, accB = 0.f;
#pragma unroll
        for (int j = 0; j < 4; ++j) {
            const uint32_t ua[4] = {gA[j].x, gA[j].y, gA[j].z, gA[j].w};
            const uint32_t ub[4] = {gB[j].x, gB[j].y, gB[j].z, gB[j].w};
#pragma unroll
            for (int m = 0; m < 4; ++m) {
                const int cb = j * 8 + m * 2;
                accA = fmaf(bf_lo(ua[m]), w[cb + 0], accA);
                accA = fmaf(bf_hi(ua[m]), w[cb + 1], accA);
                accB = fmaf(bf_lo(ub[m]), w[cb + 0], accB);
                accB = fmaf(bf_hi(ub[m]), w[cb + 1], accB);
            }
        }
        accA += __shfl_xor(accA, 32, 64);
        accB += __shfl_xor(accB, 32, 64);
        if (lane < 32) {
            atomAddF32(out + A.x * IC + c, accA);
            if (hasB) atomAddF32(out + B.x * IC + c, accB);
        }
    }
}

extern "C" void kernel_launch(void* const* d_in, const int* in_sizes, int n_in,
                              void* d_out, int out_size, void* d_ws, size_t ws_size,
                              hipStream_t stream) {
    const float* feat = (const float*)d_in[0];
    const int* coors = (const int*)d_in[1];
    const float* W1 = (const float*)d_in[2];
    const float* W2 = (const float*)d_in[3];
    float* out = (float*)d_out;

    if (ws_size < WS_NEEDED) return;  // loud failure: out stays zero

    char* ws = (char*)d_ws;
    int* keys = (int*)(ws + OFF_KEYS);
    int* vals = (int*)(ws + OFF_VALS);
    int* counter = (int*)(ws + OFF_CNT);
    int* rows = (int*)(ws + OFF_ROWS);
    uint32_t* featb = (uint32_t*)(ws + OFF_FEATB);
    uint16_t* gridb = (uint16_t*)(ws + OFF_GRID);

    k_init<<<dim3(4096), dim3(256), 0, stream>>>(keys, out, counter,
                                                 (const float2*)feat, featb);
    k_build<<<dim3((N_VOX + 255) / 256), dim3(256), 0, stream>>>(coors, keys, rows);
    k_assign<<<dim3(TBL_SIZE / 2048), dim3(256), 0, stream>>>(keys, vals, counter,
                                                              (float4*)gridb);
    k_rows_fix<<<dim3((NKV * N_VOX + 255) / 256), dim3(256), 0, stream>>>(rows, vals);

    dim3 gs((N_VOX + VPBLK - 1) / VPBLK, NKV);
    k_scatter<<<gs, dim3(256), 0, stream>>>((const uint4*)featb, W1, rows, gridb);
    k_gather<<<gs, dim3(256), 0, stream>>>(gridb, W2, rows, out);
}

// Round 6
// 280.821 us; speedup vs baseline: 1.3249x; 1.3249x over previous
//
#include <hip/hip_runtime.h>
#include <stdint.h>

// Sparse strided conv: scatter (features@W1 -> grid) + gather (grid@W2 -> out).
// R6: gather rewritten v-major with MFMA: wave owns 32 voxels, loops 27 kv,
//     masked mfma_f32_16x16x32_bf16 (A = gathered bf16 grid rows, B = W2^T
//     bf16), f32 accum across kv, ONE plain store per output. No out atomics,
//     no out zero-init, no serial per-pair chains. Scatter kept from R5.

#define N_VOX 120000
#define IC 32
#define OC 64
#define NKV 27
#define DZ 21
#define HY 200
#define WX 176
#define TBL_BITS 20
#define TBL_SIZE (1 << TBL_BITS)
#define TBL_MASK (TBL_SIZE - 1)
#define MAXROWS 480000
#define VPW 128                    // voxels scanned per wave (scatter)
#define VPBLK (VPW * 4)

// ws layout (bytes)
#define OFF_KEYS 0                 // 4 MB
#define OFF_VALS 4194304           // 4 MB
#define OFF_CNT 8388608            // 256 B
#define OFF_ROWS 8388864           // 27*120000*4 = 12,960,000
#define OFF_FEATB 21348864         // 120000*32*2 = 7,680,000
#define OFF_W2T 29028864           // 27*32*64*2 = 110,592
#define OFF_GRID 29139456          // MAXROWS*64*2 = 61,440,000
#define WS_NEEDED (OFF_GRID + (size_t)MAXROWS * OC * 2)

typedef __attribute__((ext_vector_type(8))) short short8;
typedef __attribute__((ext_vector_type(4))) float f32x4;

__device__ __forceinline__ uint32_t hash_lin(int lin) {
    return ((uint32_t)lin * 2654435761u) >> (32 - TBL_BITS);
}

__device__ __forceinline__ void atomAddF32(float* p, float v) {
    unsafeAtomicAdd(p, v);  // global_atomic_add_f32 on gfx950
}

__device__ __forceinline__ void atomPkBf16(uint16_t* p, uint32_t v) {
    asm volatile("global_atomic_pk_add_bf16 %0, %1, off" :: "v"(p), "v"(v) : "memory");
}

// RTNE f32 -> bf16 pair pack
__device__ __forceinline__ uint32_t pk_bf16(float a, float b) {
    uint32_t x = __float_as_uint(a), y = __float_as_uint(b);
    x = (x + 0x7fffu + ((x >> 16) & 1u)) >> 16;
    y = (y + 0x7fffu + ((y >> 16) & 1u)) >> 16;
    return x | (y << 16);
}
__device__ __forceinline__ uint16_t f2bf(float a) {
    uint32_t x = __float_as_uint(a);
    return (uint16_t)((x + 0x7fffu + ((x >> 16) & 1u)) >> 16);
}

__device__ __forceinline__ float bf_lo(uint32_t u) { return __uint_as_float(u << 16); }
__device__ __forceinline__ float bf_hi(uint32_t u) { return __uint_as_float(u & 0xffff0000u); }

__global__ void k_init(int* keys, int* counter,
                       const float2* __restrict__ feat2, uint32_t* featb,
                       const float* __restrict__ W2, uint16_t* w2t) {
    int i = blockIdx.x * blockDim.x + threadIdx.x;
    int stride = gridDim.x * blockDim.x;
    for (int j = i; j < TBL_SIZE; j += stride) keys[j] = -1;
    for (int j = i; j < N_VOX * IC / 2; j += stride) {
        float2 f = feat2[j];
        featb[j] = pk_bf16(f.x, f.y);
    }
    // W2 [kv][o][c] f32 -> w2t [kv][c][o] bf16
    for (int j = i; j < NKV * OC * IC; j += stride) {
        int kv = j >> 11, o = (j >> 5) & 63, c = j & 31;
        w2t[(kv << 11) + (c << 6) + o] = f2bf(W2[j]);
    }
    if (i == 0) *counter = 0;
}

__global__ void k_build(const int* __restrict__ coors, int* keys, int* rows) {
    int v = blockIdx.x * blockDim.x + threadIdx.x;
    if (v >= N_VOX) return;
    int b = coors[v * 4 + 0];
    int z = coors[v * 4 + 1];
    int y = coors[v * 4 + 2];
    int x = coors[v * 4 + 3];
#pragma unroll
    for (int kv = 0; kv < NKV; ++kv) {
        int oz = kv / 9, oy = (kv / 3) % 3, ox = kv % 3;
        int az = z + 1 - oz, ay = y + 1 - oy, ax = x + 1 - ox;
        int slot = -1;
        bool valid = (az >= 0) && !(az & 1) && ((az >> 1) < DZ) &&
                     (ay >= 0) && !(ay & 1) && ((ay >> 1) < HY) &&
                     (ax >= 0) && !(ax & 1) && ((ax >> 1) < WX);
        if (valid) {
            int lin = ((b * DZ + (az >> 1)) * HY + (ay >> 1)) * WX + (ax >> 1);
            uint32_t h = hash_lin(lin);
            for (;;) {
                int k = atomicCAS(&keys[h], -1, lin);
                if (k == -1 || k == lin) { slot = (int)h; break; }
                h = (h + 1) & TBL_MASK;
            }
        }
        rows[kv * N_VOX + v] = slot;
    }
}

// Block-aggregated compaction (1 atomic/block) + fused zeroing of the block's
// contiguous claimed row range [base, base+total). Grid row = 128 B bf16.
__global__ __launch_bounds__(256) void k_assign(const int* __restrict__ keys,
                                                int* __restrict__ vals,
                                                int* counter,
                                                float4* __restrict__ grid4) {
    const int t = threadIdx.x;
    const int s0 = blockIdx.x * 2048 + t * 8;
    const int4 a = ((const int4*)(keys + s0))[0];
    const int4 b = ((const int4*)(keys + s0))[1];
    int k[8] = {a.x, a.y, a.z, a.w, b.x, b.y, b.z, b.w};
    int c = 0;
#pragma unroll
    for (int i = 0; i < 8; ++i) c += (k[i] != -1);

    __shared__ int sc[256];
    __shared__ int base;
    sc[t] = c;
    __syncthreads();
#pragma unroll
    for (int d = 1; d < 256; d <<= 1) {
        int y = (t >= d) ? sc[t - d] : 0;
        __syncthreads();
        sc[t] += y;
        __syncthreads();
    }
    if (t == 255) base = atomicAdd(counter, sc[255]);
    __syncthreads();
    const int total = sc[255];
    int r = base + sc[t] - c;  // exclusive prefix
#pragma unroll
    for (int i = 0; i < 8; ++i) {
        if (k[i] != -1) { vals[s0 + i] = (r < MAXROWS) ? r : -1; ++r; }
    }
    int zs = min(base, MAXROWS), ze = min(base + total, MAXROWS);
    float4 zz = {0.f, 0.f, 0.f, 0.f};
    for (int i = zs * 8 + t; i < ze * 8; i += 256) grid4[i] = zz;
}

__global__ void k_rows_fix(int* rows, const int* __restrict__ vals) {
    int i = blockIdx.x * blockDim.x + threadIdx.x;
    if (i >= NKV * N_VOX) return;
    int s = rows[i];
    rows[i] = (s >= 0) ? vals[s] : -1;
}

// Ballot-compact valid (v,row) pairs of this wave's VPW voxels into its LDS
// region. One wave only -> no barrier needed.
__device__ __forceinline__ int compact_pairs(const int* __restrict__ rkv,
                                             int v0, int lane, int2* ls) {
    int n = 0;
#pragma unroll
    for (int ch = 0; ch < VPW / 64; ++ch) {
        int v = v0 + ch * 64 + lane;
        int row = (v < N_VOX) ? rkv[v] : -1;
        unsigned long long m = __ballot(row >= 0);
        int pos = n + (int)__popcll(m & ((1ULL << lane) - 1));
        if (row >= 0) ls[pos] = make_int2(v, row);
        n += (int)__popcll(m);
    }
    return n;
}

// Scatter (R5 form): 4 indep waves/block; lane = output channel. W1[kv]
// column in 32 VGPRs; bf16 feature reads; packed bf16 atomics into grid.
__global__ __launch_bounds__(256, 8) void k_scatter(
    const uint4* __restrict__ featb, const float* __restrict__ W1,
    const int* __restrict__ rows, uint16_t* gridb) {
    const int kv = blockIdx.y;
    const int wid = threadIdx.x >> 6;
    const int lane = threadIdx.x & 63;
    __shared__ int2 ls[4][VPW];

    float w[IC];
#pragma unroll
    for (int c = 0; c < IC; ++c) w[c] = W1[(kv * IC + c) * OC + lane];

    const int v0 = (blockIdx.x * 4 + wid) * VPW;
    const int n = (v0 < N_VOX)
                      ? compact_pairs(rows + kv * N_VOX, v0, lane, ls[wid])
                      : 0;

    for (int p = 0; p < n; p += 2) {
        const bool hasB = (p + 1 < n);
        const int2 A = ls[wid][p];
        const int2 B = ls[wid][hasB ? p + 1 : p];
        const uint4* pA = featb + A.x * 4;  // 32 bf16 = 4 x uint4
        const uint4* pB = featb + B.x * 4;
        uint4 fA[4], fB[4];
#pragma unroll
        for (int j = 0; j < 4; ++j) { fA[j] = pA[j]; fB[j] = pB[j]; }
        float accA = 0.f, accB = 0.f;
#pragma unroll
        for (int j = 0; j < 4; ++j) {
            const uint32_t ua[4] = {fA[j].x, fA[j].y, fA[j].z, fA[j].w};
            const uint32_t ub[4] = {fB[j].x, fB[j].y, fB[j].z, fB[j].w};
#pragma unroll
            for (int m = 0; m < 4; ++m) {
                const int cb = j * 8 + m * 2;
                accA = fmaf(bf_lo(ua[m]), w[cb + 0], accA);
                accA = fmaf(bf_hi(ua[m]), w[cb + 1], accA);
                accB = fmaf(bf_lo(ub[m]), w[cb + 0], accB);
                accB = fmaf(bf_hi(ub[m]), w[cb + 1], accB);
            }
        }
        float oA = __shfl_xor(accA, 1, 64);
        float oB = __shfl_xor(accB, 1, 64);
        if ((lane & 1) == 0) {
            atomPkBf16(gridb + (size_t)A.y * OC + lane, pk_bf16(accA, oA));
            if (hasB) atomPkBf16(gridb + (size_t)B.y * OC + lane, pk_bf16(accB, oB));
        }
    }
}

// Gather, v-major MFMA. Wave owns 32 voxels (2 M-tiles of 16); loops 27 kv;
// per kv: masked A-loads of grid rows (zero if invalid) + 4 B-frags of W2^T
// + 2x4 mfma_f32_16x16x32_bf16 into persistent f32 acc; final plain store.
// Fragment layout (guide §3, m89-verified): A/B lane=(idx&15, k=(l>>4)*8+j);
// D: col=lane&15, row=(lane>>4)*4+reg.
__global__ __launch_bounds__(256) void k_gather_v(
    const uint16_t* __restrict__ gridb, const uint16_t* __restrict__ w2t,
    const int* __restrict__ rows, float* __restrict__ out) {
    const int wid = threadIdx.x >> 6;
    const int lane = threadIdx.x & 63;
    const int v0 = (blockIdx.x * 4 + wid) * 32;
    if (v0 >= N_VOX) return;
    const int lg = lane >> 4;   // k-group (inputs) / row-group (output)
    const int li = lane & 15;   // m (A) / n (B) / col (D)

    f32x4 acc[2][2] = {{{0.f, 0.f, 0.f, 0.f}, {0.f, 0.f, 0.f, 0.f}},
                       {{0.f, 0.f, 0.f, 0.f}, {0.f, 0.f, 0.f, 0.f}}};

    for (int kv = 0; kv < NKV; ++kv) {
        const int* rkv = rows + kv * N_VOX;
        const uint16_t* w2k = w2t + ((size_t)kv << 11);
        short8 b[2][2];  // [ntile][khalf]
#pragma unroll
        for (int nt = 0; nt < 2; ++nt)
#pragma unroll
            for (int kh = 0; kh < 2; ++kh)
                b[nt][kh] = *(const short8*)(w2k + (nt * 16 + li) * 64 +
                                             kh * 32 + lg * 8);
#pragma unroll
        for (int mt = 0; mt < 2; ++mt) {
            const int v = v0 + mt * 16 + li;
            const int r = (v < N_VOX) ? rkv[v] : -1;
            short8 a0 = {0, 0, 0, 0, 0, 0, 0, 0};
            short8 a1 = {0, 0, 0, 0, 0, 0, 0, 0};
            if (r >= 0) {
                const uint16_t* gr = gridb + (size_t)r * OC;
                a0 = *(const short8*)(gr + lg * 8);        // k = 0..31
                a1 = *(const short8*)(gr + 32 + lg * 8);   // k = 32..63
            }
            acc[mt][0] = __builtin_amdgcn_mfma_f32_16x16x32_bf16(a0, b[0][0], acc[mt][0], 0, 0, 0);
            acc[mt][0] = __builtin_amdgcn_mfma_f32_16x16x32_bf16(a1, b[0][1], acc[mt][0], 0, 0, 0);
            acc[mt][1] = __builtin_amdgcn_mfma_f32_16x16x32_bf16(a0, b[1][0], acc[mt][1], 0, 0, 0);
            acc[mt][1] = __builtin_amdgcn_mfma_f32_16x16x32_bf16(a1, b[1][1], acc[mt][1], 0, 0, 0);
        }
    }
#pragma unroll
    for (int mt = 0; mt < 2; ++mt)
#pragma unroll
        for (int nt = 0; nt < 2; ++nt)
#pragma unroll
            for (int rg = 0; rg < 4; ++rg) {
                const int v = v0 + mt * 16 + lg * 4 + rg;
                if (v < N_VOX) out[(size_t)v * IC + nt * 16 + li] = acc[mt][nt][rg];
            }
}

extern "C" void kernel_launch(void* const* d_in, const int* in_sizes, int n_in,
                              void* d_out, int out_size, void* d_ws, size_t ws_size,
                              hipStream_t stream) {
    const float* feat = (const float*)d_in[0];
    const int* coors = (const int*)d_in[1];
    const float* W1 = (const float*)d_in[2];
    const float* W2 = (const float*)d_in[3];
    float* out = (float*)d_out;

    if (ws_size < WS_NEEDED) return;  // loud failure: out stays poisoned

    char* ws = (char*)d_ws;
    int* keys = (int*)(ws + OFF_KEYS);
    int* vals = (int*)(ws + OFF_VALS);
    int* counter = (int*)(ws + OFF_CNT);
    int* rows = (int*)(ws + OFF_ROWS);
    uint32_t* featb = (uint32_t*)(ws + OFF_FEATB);
    uint16_t* w2t = (uint16_t*)(ws + OFF_W2T);
    uint16_t* gridb = (uint16_t*)(ws + OFF_GRID);

    k_init<<<dim3(4096), dim3(256), 0, stream>>>(keys, counter,
                                                 (const float2*)feat, featb,
                                                 W2, w2t);
    k_build<<<dim3((N_VOX + 255) / 256), dim3(256), 0, stream>>>(coors, keys, rows);
    k_assign<<<dim3(TBL_SIZE / 2048), dim3(256), 0, stream>>>(keys, vals, counter,
                                                              (float4*)gridb);
    k_rows_fix<<<dim3((NKV * N_VOX + 255) / 256), dim3(256), 0, stream>>>(rows, vals);

    dim3 gs((N_VOX + VPBLK - 1) / VPBLK, NKV);
    k_scatter<<<gs, dim3(256), 0, stream>>>((const uint4*)featb, W1, rows, gridb);

    k_gather_v<<<dim3((N_VOX + 127) / 128), dim3(256), 0, stream>>>(gridb, w2t,
                                                                    rows, out);
}

// Round 7
// 226.612 us; speedup vs baseline: 1.6418x; 1.2392x over previous
//
#include <hip/hip_runtime.h>
#include <stdint.h>

// Sparse strided conv: scatter (features@W1 -> grid) + gather (grid@W2 -> out).
// R7: scatter rewritten v-major MFMA (mirror of R6's gather win):
//     wave owns 32 voxels, A(feat) frags loaded ONCE (kv-invariant), loop 27 kv:
//     {4 B-frags W1^T + row-ids + 8 mfma_16x16x32_bf16 + masked pk-bf16 atomic
//     scatter of D}. No serial unpack chain, atomics fire-and-forget.

#define N_VOX 120000
#define IC 32
#define OC 64
#define NKV 27
#define DZ 21
#define HY 200
#define WX 176
#define TBL_BITS 20
#define TBL_SIZE (1 << TBL_BITS)
#define TBL_MASK (TBL_SIZE - 1)
#define MAXROWS 480000

// ws layout (bytes)
#define OFF_KEYS 0                 // 4 MB
#define OFF_VALS 4194304           // 4 MB
#define OFF_CNT 8388608            // 256 B
#define OFF_ROWS 8388864           // 27*120000*4 = 12,960,000
#define OFF_FEATB 21348864         // 120000*32*2 = 7,680,000
#define OFF_W2T 29028864           // 27*32*64*2 = 110,592
#define OFF_W1T 29139456           // 27*64*32*2 = 110,592
#define OFF_GRID 29250048          // MAXROWS*64*2 = 61,440,000
#define WS_NEEDED (OFF_GRID + (size_t)MAXROWS * OC * 2)

typedef __attribute__((ext_vector_type(8))) short short8;
typedef __attribute__((ext_vector_type(4))) float f32x4;

__device__ __forceinline__ uint32_t hash_lin(int lin) {
    return ((uint32_t)lin * 2654435761u) >> (32 - TBL_BITS);
}

__device__ __forceinline__ void atomPkBf16(uint16_t* p, uint32_t v) {
    asm volatile("global_atomic_pk_add_bf16 %0, %1, off" :: "v"(p), "v"(v) : "memory");
}

// RTNE f32 -> bf16 pair pack
__device__ __forceinline__ uint32_t pk_bf16(float a, float b) {
    uint32_t x = __float_as_uint(a), y = __float_as_uint(b);
    x = (x + 0x7fffu + ((x >> 16) & 1u)) >> 16;
    y = (y + 0x7fffu + ((y >> 16) & 1u)) >> 16;
    return x | (y << 16);
}
__device__ __forceinline__ uint16_t f2bf(float a) {
    uint32_t x = __float_as_uint(a);
    return (uint16_t)((x + 0x7fffu + ((x >> 16) & 1u)) >> 16);
}

__global__ void k_init(int* keys, int* counter,
                       const float2* __restrict__ feat2, uint32_t* featb,
                       const float* __restrict__ W1, uint16_t* w1t,
                       const float* __restrict__ W2, uint16_t* w2t) {
    int i = blockIdx.x * blockDim.x + threadIdx.x;
    int stride = gridDim.x * blockDim.x;
    for (int j = i; j < TBL_SIZE; j += stride) keys[j] = -1;
    for (int j = i; j < N_VOX * IC / 2; j += stride) {
        float2 f = feat2[j];
        featb[j] = pk_bf16(f.x, f.y);
    }
    // W1 [kv][c][o] f32 -> w1t [kv][o][c] bf16
    for (int j = i; j < NKV * IC * OC; j += stride) {
        int kv = j >> 11, c = (j >> 6) & 31, o = j & 63;
        w1t[(kv << 11) + (o << 5) + c] = f2bf(W1[j]);
    }
    // W2 [kv][o][c] f32 -> w2t [kv][c][o] bf16
    for (int j = i; j < NKV * OC * IC; j += stride) {
        int kv = j >> 11, o = (j >> 5) & 63, c = j & 31;
        w2t[(kv << 11) + (c << 6) + o] = f2bf(W2[j]);
    }
    if (i == 0) *counter = 0;
}

__global__ void k_build(const int* __restrict__ coors, int* keys, int* rows) {
    int v = blockIdx.x * blockDim.x + threadIdx.x;
    if (v >= N_VOX) return;
    int b = coors[v * 4 + 0];
    int z = coors[v * 4 + 1];
    int y = coors[v * 4 + 2];
    int x = coors[v * 4 + 3];
#pragma unroll
    for (int kv = 0; kv < NKV; ++kv) {
        int oz = kv / 9, oy = (kv / 3) % 3, ox = kv % 3;
        int az = z + 1 - oz, ay = y + 1 - oy, ax = x + 1 - ox;
        int slot = -1;
        bool valid = (az >= 0) && !(az & 1) && ((az >> 1) < DZ) &&
                     (ay >= 0) && !(ay & 1) && ((ay >> 1) < HY) &&
                     (ax >= 0) && !(ax & 1) && ((ax >> 1) < WX);
        if (valid) {
            int lin = ((b * DZ + (az >> 1)) * HY + (ay >> 1)) * WX + (ax >> 1);
            uint32_t h = hash_lin(lin);
            for (;;) {
                int k = atomicCAS(&keys[h], -1, lin);
                if (k == -1 || k == lin) { slot = (int)h; break; }
                h = (h + 1) & TBL_MASK;
            }
        }
        rows[kv * N_VOX + v] = slot;
    }
}

// Block-aggregated compaction (1 atomic/block) + fused zeroing of the block's
// contiguous claimed row range [base, base+total). Grid row = 128 B bf16.
__global__ __launch_bounds__(256) void k_assign(const int* __restrict__ keys,
                                                int* __restrict__ vals,
                                                int* counter,
                                                float4* __restrict__ grid4) {
    const int t = threadIdx.x;
    const int s0 = blockIdx.x * 2048 + t * 8;
    const int4 a = ((const int4*)(keys + s0))[0];
    const int4 b = ((const int4*)(keys + s0))[1];
    int k[8] = {a.x, a.y, a.z, a.w, b.x, b.y, b.z, b.w};
    int c = 0;
#pragma unroll
    for (int i = 0; i < 8; ++i) c += (k[i] != -1);

    __shared__ int sc[256];
    __shared__ int base;
    sc[t] = c;
    __syncthreads();
#pragma unroll
    for (int d = 1; d < 256; d <<= 1) {
        int y = (t >= d) ? sc[t - d] : 0;
        __syncthreads();
        sc[t] += y;
        __syncthreads();
    }
    if (t == 255) base = atomicAdd(counter, sc[255]);
    __syncthreads();
    const int total = sc[255];
    int r = base + sc[t] - c;  // exclusive prefix
#pragma unroll
    for (int i = 0; i < 8; ++i) {
        if (k[i] != -1) { vals[s0 + i] = (r < MAXROWS) ? r : -1; ++r; }
    }
    int zs = min(base, MAXROWS), ze = min(base + total, MAXROWS);
    float4 zz = {0.f, 0.f, 0.f, 0.f};
    for (int i = zs * 8 + t; i < ze * 8; i += 256) grid4[i] = zz;
}

__global__ void k_rows_fix(int* rows, const int* __restrict__ vals) {
    int i = blockIdx.x * blockDim.x + threadIdx.x;
    if (i >= NKV * N_VOX) return;
    int s = rows[i];
    rows[i] = (s >= 0) ? vals[s] : -1;
}

// Scatter, v-major MFMA. Wave owns 32 voxels (N_VOX%32==0 -> full waves).
// A = feat bf16 tiles (loaded once, kv-invariant). Per kv: B = W1^T frags,
// 8 mfma into fresh D, scatter D via pk-bf16 atomics to grid rows.
// D layout (m89): col(channel)=lane&15, row(voxel)=(lane>>4)*4+reg.
__global__ __launch_bounds__(256) void k_scatter_v(
    const uint16_t* __restrict__ featb, const uint16_t* __restrict__ w1t,
    const int* __restrict__ rows, uint16_t* gridb) {
    const int wid = threadIdx.x >> 6;
    const int lane = threadIdx.x & 63;
    const int v0 = (blockIdx.x * 4 + wid) * 32;
    if (v0 >= N_VOX) return;
    const int lg = lane >> 4;
    const int li = lane & 15;

    short8 a[2];
#pragma unroll
    for (int mt = 0; mt < 2; ++mt)
        a[mt] = *(const short8*)(featb + (size_t)(v0 + mt * 16 + li) * IC + lg * 8);

    for (int kv = 0; kv < NKV; ++kv) {
        const int* rkv = rows + kv * N_VOX;
        const uint16_t* w1k = w1t + (kv << 11);
        short8 b[4];
#pragma unroll
        for (int nt = 0; nt < 4; ++nt)
            b[nt] = *(const short8*)(w1k + (nt * 16 + li) * IC + lg * 8);
        int4 r4[2];
#pragma unroll
        for (int mt = 0; mt < 2; ++mt)
            r4[mt] = *(const int4*)(rkv + v0 + mt * 16 + lg * 4);
#pragma unroll
        for (int mt = 0; mt < 2; ++mt) {
            const int rr[4] = {r4[mt].x, r4[mt].y, r4[mt].z, r4[mt].w};
#pragma unroll
            for (int nt = 0; nt < 4; ++nt) {
                f32x4 d = {0.f, 0.f, 0.f, 0.f};
                d = __builtin_amdgcn_mfma_f32_16x16x32_bf16(a[mt], b[nt], d, 0, 0, 0);
#pragma unroll
                for (int rg = 0; rg < 4; ++rg) {
                    float other = __shfl_xor(d[rg], 1, 64);
                    if ((li & 1) == 0 && rr[rg] >= 0) {
                        atomPkBf16(gridb + (size_t)rr[rg] * OC + nt * 16 + li,
                                   pk_bf16(d[rg], other));
                    }
                }
            }
        }
    }
}

// Gather, v-major MFMA (R6, unchanged). Wave owns 32 voxels; loops 27 kv;
// masked A-loads of grid rows + W2^T B-frags; f32 accum; one plain store.
__global__ __launch_bounds__(256) void k_gather_v(
    const uint16_t* __restrict__ gridb, const uint16_t* __restrict__ w2t,
    const int* __restrict__ rows, float* __restrict__ out) {
    const int wid = threadIdx.x >> 6;
    const int lane = threadIdx.x & 63;
    const int v0 = (blockIdx.x * 4 + wid) * 32;
    if (v0 >= N_VOX) return;
    const int lg = lane >> 4;
    const int li = lane & 15;

    f32x4 acc[2][2] = {{{0.f, 0.f, 0.f, 0.f}, {0.f, 0.f, 0.f, 0.f}},
                       {{0.f, 0.f, 0.f, 0.f}, {0.f, 0.f, 0.f, 0.f}}};

    for (int kv = 0; kv < NKV; ++kv) {
        const int* rkv = rows + kv * N_VOX;
        const uint16_t* w2k = w2t + ((size_t)kv << 11);
        short8 b[2][2];  // [ntile][khalf]
#pragma unroll
        for (int nt = 0; nt < 2; ++nt)
#pragma unroll
            for (int kh = 0; kh < 2; ++kh)
                b[nt][kh] = *(const short8*)(w2k + (nt * 16 + li) * 64 +
                                             kh * 32 + lg * 8);
#pragma unroll
        for (int mt = 0; mt < 2; ++mt) {
            const int v = v0 + mt * 16 + li;
            const int r = rkv[v];
            short8 a0 = {0, 0, 0, 0, 0, 0, 0, 0};
            short8 a1 = {0, 0, 0, 0, 0, 0, 0, 0};
            if (r >= 0) {
                const uint16_t* gr = gridb + (size_t)r * OC;
                a0 = *(const short8*)(gr + lg * 8);        // k = 0..31
                a1 = *(const short8*)(gr + 32 + lg * 8);   // k = 32..63
            }
            acc[mt][0] = __builtin_amdgcn_mfma_f32_16x16x32_bf16(a0, b[0][0], acc[mt][0], 0, 0, 0);
            acc[mt][0] = __builtin_amdgcn_mfma_f32_16x16x32_bf16(a1, b[0][1], acc[mt][0], 0, 0, 0);
            acc[mt][1] = __builtin_amdgcn_mfma_f32_16x16x32_bf16(a0, b[1][0], acc[mt][1], 0, 0, 0);
            acc[mt][1] = __builtin_amdgcn_mfma_f32_16x16x32_bf16(a1, b[1][1], acc[mt][1], 0, 0, 0);
        }
    }
#pragma unroll
    for (int mt = 0; mt < 2; ++mt)
#pragma unroll
        for (int nt = 0; nt < 2; ++nt)
#pragma unroll
            for (int rg = 0; rg < 4; ++rg) {
                const int v = v0 + mt * 16 + lg * 4 + rg;
                out[(size_t)v * IC + nt * 16 + li] = acc[mt][nt][rg];
            }
}

extern "C" void kernel_launch(void* const* d_in, const int* in_sizes, int n_in,
                              void* d_out, int out_size, void* d_ws, size_t ws_size,
                              hipStream_t stream) {
    const float* feat = (const float*)d_in[0];
    const int* coors = (const int*)d_in[1];
    const float* W1 = (const float*)d_in[2];
    const float* W2 = (const float*)d_in[3];
    float* out = (float*)d_out;

    if (ws_size < WS_NEEDED) return;  // loud failure: out stays poisoned

    char* ws = (char*)d_ws;
    int* keys = (int*)(ws + OFF_KEYS);
    int* vals = (int*)(ws + OFF_VALS);
    int* counter = (int*)(ws + OFF_CNT);
    int* rows = (int*)(ws + OFF_ROWS);
    uint32_t* featb = (uint32_t*)(ws + OFF_FEATB);
    uint16_t* w2t = (uint16_t*)(ws + OFF_W2T);
    uint16_t* w1t = (uint16_t*)(ws + OFF_W1T);
    uint16_t* gridb = (uint16_t*)(ws + OFF_GRID);

    k_init<<<dim3(4096), dim3(256), 0, stream>>>(keys, counter,
                                                 (const float2*)feat, featb,
                                                 W1, w1t, W2, w2t);
    k_build<<<dim3((N_VOX + 255) / 256), dim3(256), 0, stream>>>(coors, keys, rows);
    k_assign<<<dim3(TBL_SIZE / 2048), dim3(256), 0, stream>>>(keys, vals, counter,
                                                              (float4*)gridb);
    k_rows_fix<<<dim3((NKV * N_VOX + 255) / 256), dim3(256), 0, stream>>>(rows, vals);

    const int nblk = (N_VOX + 127) / 128;  // 4 waves/block, 32 vox/wave
    k_scatter_v<<<dim3(nblk), dim3(256), 0, stream>>>((const uint16_t*)featb,
                                                      w1t, rows, gridb);
    k_gather_v<<<dim3(nblk), dim3(256), 0, stream>>>(gridb, w2t, rows, out);
}